// Round 9
// baseline (813.719 us; speedup 1.0000x reference)
//
#include <hip/hip_runtime.h>
#include <math.h>

#define TT 4096
#define DD 64
#define CC 32
#define KK 20
#define TPE 4128   /* transposed eT row stride: 4096 + 32 pad for prefetch overrun */
#define L2E 1.44269504088896340736f
#define LN2f 0.69314718055994530942f
#define PIN 10.0f  /* wave-max pf pinned near 2^-PIN (symmetric float headroom) */

typedef float v2 __attribute__((ext_vector_type(2)));

#if __has_builtin(__builtin_amdgcn_permlane32_swap)
#define HAVE_PLSWAP 1
#endif
#if __has_builtin(__builtin_amdgcn_permlane16_swap)
#define HAVE_PL16 1
#endif

// ---- static device scratch ----
__device__ __align__(16) float g_pmu[32 * 64];
__device__ __align__(16) float g_p2[64];
__device__ __align__(16) float g_mc[32];
__device__ __align__(16) float g_ls2[20 * 32];
__device__ __align__(16) float g_T[32 * 32];
__device__ __align__(16) float g_init2[32];
__device__ float g_mb;
__device__ __align__(16) float g_eT[8 * 32 * TPE];

__device__ __forceinline__ float fexp2(float x) {
#if __has_builtin(__builtin_amdgcn_exp2f)
    return __builtin_amdgcn_exp2f(x);
#else
    return __exp2f(x);
#endif
}
__device__ __forceinline__ float flog2(float x) {
#if __has_builtin(__builtin_amdgcn_logf)
    return __builtin_amdgcn_logf(x);
#else
    return __log2f(x);
#endif
}

#define RF(x) __int_as_float(__builtin_amdgcn_readfirstlane(__float_as_int(x)))

// cross-half exchange (validated r1/r2/r4/r7 — runtime select, polarity-proof)
__device__ __forceinline__ float xswap32(float x) {
#ifdef HAVE_PLSWAP
    int xi = __float_as_int(x);
    auto pr = __builtin_amdgcn_permlane32_swap(xi, xi, false, false);
    int r0 = ((const int*)&pr)[0];
    int r1 = ((const int*)&pr)[1];
    return (r0 == xi) ? __int_as_float(r1) : __int_as_float(r0);
#else
    return __shfl_xor(x, 32);
#endif
}
__device__ __forceinline__ float xswap16(float x) {
#ifdef HAVE_PL16
    int xi = __float_as_int(x);
    auto pr = __builtin_amdgcn_permlane16_swap(xi, xi, false, false);
    int r0 = ((const int*)&pr)[0];
    int r1 = ((const int*)&pr)[1];
    return (r0 == xi) ? __int_as_float(r1) : __int_as_float(r0);
#else
    return __shfl_xor(x, 16);
#endif
}

// XOR-symmetric DPP: 0xB1=xor1 0x4E=xor2 0x141=xor7 0x140=xor15
#define DPPF(dst, src, CTRL) \
    dst = __int_as_float(__builtin_amdgcn_update_dpp(0, __float_as_int(src), (CTRL), 0xF, 0xF, 1))

// 64-lane max via XOR butterflies (r7-validated)
__device__ __forceinline__ float wmax64(float x) {
    float m = x, t;
    DPPF(t, m, 0xB1);  m = fmaxf(m, t);
    DPPF(t, m, 0x4E);  m = fmaxf(m, t);
    DPPF(t, m, 0x141); m = fmaxf(m, t);
    DPPF(t, m, 0x140); m = fmaxf(m, t);
    m = fmaxf(m, xswap16(m));
    m = fmaxf(m, xswap32(m));
    return m;
}

// ---------------- setup ----------------
__global__ void smm_setup(const float* __restrict__ plr,
                          const float* __restrict__ mu,
                          const float* __restrict__ cov,
                          const float* __restrict__ tl,
                          const float* __restrict__ il) {
    int l = threadIdx.x;
    __shared__ float red[64];
    __shared__ float redp[64];
    __shared__ float muP[32];
    __shared__ float constc_s;
    float cd = cov[l * 64 + l];
    float pd = 1.0f / cd;
    red[l] = logf(cd);
    redp[l] = pd;
    __syncthreads();
    if (l == 0) {
        float s = 0.f;
        for (int i = 0; i < 64; ++i) s += red[i];
        constc_s = 64.0f * logf(2.0f * 3.14159265358979323846f) + s;
    }
    __syncthreads();
    float constc = constc_s;

    g_p2[l] = 0.5f * L2E * pd;
    for (int c2 = 0; c2 < 32; ++c2)
        g_pmu[c2 * 64 + l] = L2E * pd * mu[c2 * 64 + l];

    if (l < 32) {
        float s = 0.f;
        for (int d2 = 0; d2 < 64; ++d2) {
            float m_ = mu[l * 64 + d2];
            s += m_ * m_ / cov[d2 * 64 + d2];
        }
        g_mc[l] = -0.5f * L2E * (s + constc);
        muP[l] = s;
    }
    for (int idx = l; idx < KK * CC; idx += 64) {
        int k = idx >> 5, c2 = idx & 31;
        float lr = plr[c2];
        g_ls2[idx] = L2E * ((float)(k + 1) * lr - expf(lr) - lgammaf((float)(k + 2)));
    }
    if (l < 32) {
        int from = l;
        float mx = -1e30f;
        for (int to = 0; to < 32; ++to) mx = fmaxf(mx, tl[to * 32 + from]);
        float s = 0.f;
        for (int to = 0; to < 32; ++to) s += expf(tl[to * 32 + from] - mx);
        float inv = 1.0f / s;
        for (int to = 0; to < 32; ++to)
            g_T[to * 32 + from] = expf(tl[to * 32 + from] - mx) * inv;
    }
    if (l == 32) {
        float mx = -1e30f;
        for (int c2 = 0; c2 < 32; ++c2) mx = fmaxf(mx, il[c2]);
        float s = 0.f;
        for (int c2 = 0; c2 < 32; ++c2) s += expf(il[c2] - mx);
        float lse = mx + logf(s);
        for (int c2 = 0; c2 < 32; ++c2) g_init2[c2] = L2E * (il[c2] - lse);
    }
    __syncthreads();
    if (l == 0) {
        float trP = 0.f;
        for (int i = 0; i < 64; ++i) trP += redp[i];
        float mm = 0.f;
        for (int c2 = 0; c2 < 32; ++c2) mm += muP[c2];
        mm *= (1.0f / 32.0f);
        g_mb = -0.5f * L2E * (constc + trP + mm);
    }
}

// ---------------- emit: transposed linear emission factors ----------------
__global__ __launch_bounds__(256) void smm_emit(const float* __restrict__ feat) {
    int tid = threadIdx.x;
    int c = tid & 31, tl_ = tid >> 5;
    int t = blockIdx.x * 8 + tl_;
    int b = blockIdx.y;
    const float4* x4 = (const float4*)(feat + ((size_t)b * TT + t) * DD);
    const float4* pm4 = (const float4*)(g_pmu + c * 64);
    const float4* p24 = (const float4*)g_p2;
    float acc = g_mc[c];
#pragma unroll
    for (int i = 0; i < 16; ++i) {
        float4 xv = x4[i], pm = pm4[i], pv = p24[i];
        acc = fmaf(pm.x, xv.x, acc); acc = fmaf(-pv.x * xv.x, xv.x, acc);
        acc = fmaf(pm.y, xv.y, acc); acc = fmaf(-pv.y * xv.y, xv.y, acc);
        acc = fmaf(pm.z, xv.z, acc); acc = fmaf(-pv.z * xv.z, xv.z, acc);
        acc = fmaf(pm.w, xv.w, acc); acc = fmaf(-pv.w * xv.w, xv.w, acc);
    }
    float ev = fexp2(acc - g_mb);
    __shared__ float stage[32][9];
    stage[c][tl_] = ev;
    __syncthreads();
    int c2 = tid >> 3, j = tid & 7;
    int t0 = blockIdx.x * 8;
    int ti = (t0 + j + TT - 1) & (TT - 1);
    g_eT[((size_t)b * 32 + c2) * TPE + ti] = stage[c2][j];
}

// ---- gather + matvec + pair-combine: LDS broadcast gather ----
// pf is duplicated across halves (verified r4/r7/r8 absmax 0.0), so each lane
// reads its row's 16 values from lds_p[(l&48)..+15] in IDENTITY order; Tr is
// loaded identity-ordered. Single wave -> DS FIFO keeps write->read ordered,
// no barrier. Same fma order as before -> bit-identical accl.
#define GMV(PF, OUT)                                                              \
    {                                                                             \
        lds_p[l] = (PF);                                                          \
        float4 q0 = qp[0], q1 = qp[1], q2 = qp[2], q3 = qp[3];                    \
        float a0 = Tr[0]*q0.x;  a0 = fmaf(Tr[1],q0.y,a0);  a0 = fmaf(Tr[2],q0.z,a0);  a0 = fmaf(Tr[3],q0.w,a0);   \
        float a1 = Tr[4]*q1.x;  a1 = fmaf(Tr[5],q1.y,a1);  a1 = fmaf(Tr[6],q1.z,a1);  a1 = fmaf(Tr[7],q1.w,a1);   \
        float a2 = Tr[8]*q2.x;  a2 = fmaf(Tr[9],q2.y,a2);  a2 = fmaf(Tr[10],q2.z,a2); a2 = fmaf(Tr[11],q2.w,a2);  \
        float a3 = Tr[12]*q3.x; a3 = fmaf(Tr[13],q3.y,a3); a3 = fmaf(Tr[14],q3.z,a3); a3 = fmaf(Tr[15],q3.w,a3);  \
        float accl_ = (a0 + a1) + (a2 + a3);                                      \
        OUT = accl_ + xswap16(xswap32(accl_));                                    \
    }

// ---- full scalar step with capture + per-step refc advance (r7 verbatim) ----
#define STEPS(EV, tcur)                                                           \
    {                                                                             \
        float pf = fmaf(accf, nu, OFF);                                           \
        float naccf;                                                              \
        GMV(pf, naccf)                                                            \
        pfc = pf;                                                                 \
        if ((tcur) == lenm1) { pfL = pf; refL = refc; }                           \
        float sg = (EV) * su;                                                     \
        float u2 = accf * nu;                                                     \
        float s0 = half ? Wc : u2;                                                \
        float e9 = z9 * sg;                                                       \
        float t9 = e9 * rr;                                                       \
        float x9 = xswap32(t9);                                                   \
        float Wn = half ? x9 : t9;                                                \
        z9 = z8*sg; z8 = z7*sg; z7 = z6*sg; z6 = z5*sg; z5 = z4*sg;               \
        z4 = z3*sg; z3 = z2*sg; z2 = z1*sg; z1 = s0*sg;                           \
        float tA = Pw1*z1; tA = fmaf(Pw2,z2,tA); tA = fmaf(Pw3,z3,tA);            \
        tA = fmaf(Pw4,z4,tA); tA = fmaf(Pw5,z5,tA);                               \
        float tB = Pw6*z6; tB = fmaf(Pw7,z7,tB); tB = fmaf(Pw8,z8,tB);            \
        tB = fmaf(Pw9,z9,tB);                                                     \
        float S = tA + tB;                                                        \
        float Sx = xswap32(S);                                                    \
        OFF = fmaxf((S + Sx) + Wn, 1e-36f);                                       \
        nu = sg * E1;                                                             \
        accf = naccf;                                                             \
        Wc = Wn;                                                                  \
        refc += (double)r8;                                                       \
    }

// ---- fused 2-step (r8 verbatim apart from GMV internals) ----
#define STEP2(EVA, EVB)                                                           \
    {                                                                             \
        float pfA = fmaf(accf, nu, OFF);                                          \
        float naccfA;                                                             \
        GMV(pfA, naccfA)                                                          \
        pfc = pfA;                                                                \
        float sgA = (EVA) * su;                                                   \
        float u2A = accf * nu;                                                    \
        float s0A = half ? Wc : u2A;                                              \
        float t9A = (z9 * sgA) * rr;                                              \
        float x9A = xswap32(t9A);                                                 \
        float WnA = half ? x9A : t9A;                                             \
        v2 dB = PwB1 * P1;                                                        \
        dB = __builtin_elementwise_fma(PwB2, P2, dB);                             \
        dB = __builtin_elementwise_fma(PwB3, P3, dB);                             \
        dB = __builtin_elementwise_fma(PwB4, P4, dB);                             \
        float SA = sgA * fmaf(Pw1, s0A, dB.x + dB.y);                             \
        float OFFB = fmaxf((SA + xswap32(SA)) + WnA, 1e-36f);                     \
        float nuB = sgA * E1;                                                     \
        float pfB = fmaf(naccfA, nuB, OFFB);                                      \
        float naccfB;                                                             \
        GMV(pfB, naccfB)                                                          \
        float sgB = (EVB) * su;                                                   \
        float ss = sgA * sgB;                                                     \
        float u2B = naccfA * nuB;                                                 \
        float s0B = half ? WnA : u2B;                                             \
        float t9B = (P4.y * ss) * rr;                                             \
        float x9B = xswap32(t9B);                                                 \
        float WnB = half ? x9B : t9B;                                             \
        v2 dC = PwC1 * P1;                                                        \
        dC = __builtin_elementwise_fma(PwC2, P2, dC);                             \
        dC = __builtin_elementwise_fma(PwC3, P3, dC);                             \
        dC = __builtin_elementwise_fma(PwC4, P4, dC);                             \
        float innerB = fmaf(Pw2, s0A, dC.x + dC.y);                               \
        float SB = sgB * fmaf(sgA, innerB, Pw1 * s0B);                            \
        float OFFn = fmaxf((SB + xswap32(SB)) + WnB, 1e-36f);                     \
        v2 ssv = {ss, ss};                                                        \
        z9 = P4.x * ss;                                                           \
        P4 = P3 * ssv; P3 = P2 * ssv; P2 = P1 * ssv;                              \
        v2 nP1; nP1.x = s0B * sgB; nP1.y = s0A * ss;                              \
        P1 = nP1;                                                                 \
        OFF = OFFn; nu = sgB * E1; accf = naccfB; Wc = WnB;                       \
    }

// prologue deadbeat: wave-MAX pin, per-step (r7 verbatim)
#define CTRLDB(gain)                                                              \
    {                                                                             \
        float err = flog2(wmax64(pfc)) + PIN;                                     \
        err = fminf(fmaxf(err, -50.0f), 50.0f);                                   \
        float cs = fexp2(-err);                                                   \
        accf *= cs; OFF *= cs; Wc *= cs;                                          \
        z1*=cs; z2*=cs; z3*=cs; z4*=cs; z5*=cs;                                   \
        z6*=cs; z7*=cs; z8*=cs; z9*=cs;                                           \
        refc += (double)err;                                                      \
        r8 = fmaf(err, (gain), r8);                                               \
        su = fexp2(mb - r8);                                                      \
    }

// main-loop deadbeat: wave-MAX pin, cadence 4, 1-stale (r8 verbatim)
#define CTRL2M(gain)                                                              \
    {                                                                             \
        float err = flog2(wmax64(pfc)) + PIN;                                     \
        err = fminf(fmaxf(err, -50.0f), 50.0f);                                   \
        float cs = fexp2(-err);                                                   \
        v2 csv = {cs, cs};                                                        \
        accf *= cs; OFF *= cs; Wc *= cs; z9 *= cs;                                \
        P1 *= csv; P2 *= csv; P3 *= csv; P4 *= csv;                               \
        refc += (double)err + (double)(4.0f * r8);                                \
        r8 = fmaf(err, (gain), r8);                                               \
        su = fexp2(mb - r8);                                                      \
    }

__global__ __launch_bounds__(64, 1)
void smm_forward(const int* __restrict__ lens, float* __restrict__ out) {
    const int b = blockIdx.x;
    const int l = threadIdx.x;
    const int c = l & 31;
    const int half = l >> 5;
    const int rb = ((l >> 4) & 1) * 16;
    const int cT = half ? (c ^ 16) : c;

    // LDS broadcast buffer for the gather (single wave: DS FIFO ordering, no barrier)
    __shared__ __align__(16) float lds_p[64];
    const float4* qp = (const float4*)&lds_p[l & 48];

    float lsr[10];
#pragma unroll
    for (int i = 0; i < 10; ++i) lsr[i] = g_ls2[(half * 10 + i) * 32 + c];

    // transition row, IDENTITY order (LDS gather is un-permuted):
    // lane l dots T[cT][rb+j] with lds_p[(l&48)+j] = pf(class rb+j)
    float Tr[16];
#pragma unroll
    for (int j2 = 0; j2 < 16; ++j2) Tr[j2] = g_T[cT * 32 + rb + j2];

    float tswp = __shfl_xor(lsr[0], 32);
    float ls1c = half ? tswp : lsr[0];
    float d11s = half ? lsr[0] : tswp;

    float Pw1 = fexp2(lsr[1] - lsr[0]), Pw2 = fexp2(lsr[2] - lsr[0]);
    float Pw3 = fexp2(lsr[3] - lsr[0]), Pw4 = fexp2(lsr[4] - lsr[0]);
    float Pw5 = fexp2(lsr[5] - lsr[0]), Pw6 = fexp2(lsr[6] - lsr[0]);
    float Pw7 = fexp2(lsr[7] - lsr[0]), Pw8 = fexp2(lsr[8] - lsr[0]);
    float Pw9 = fexp2(lsr[9] - lsr[0]);
    float rr  = fexp2(d11s - lsr[0]);
    float E1  = fexp2(ls1c);

    // packed weight pairs for the fused dots
    v2 PwB1 = {Pw2, Pw3}, PwB2 = {Pw4, Pw5}, PwB3 = {Pw6, Pw7}, PwB4 = {Pw8, Pw9};
    v2 PwC1 = {Pw3, Pw4}, PwC2 = {Pw5, Pw6}, PwC3 = {Pw7, Pw8}, PwC4 = {Pw9, 0.0f};

    int len = lens[b];
    if (len < 16) len = 16;
    if (len > TT) len = TT;
    const int lenm1 = len - 1;
    const int tb_end = lenm1 & ~7;   // tail block [tb_end, tb_end+7] contains lenm1

    const float* eT = g_eT + ((size_t)b * 32 + c) * TPE;
    const float4* cp = (const float4*)eT;
    float4 cA = cp[0], cB = cp[1], pA = cp[2], pB = cp[3];

    // ---- bootstrap at t=0: pin = wave-max of a0v ----
    float mb = g_mb;
    float e0 = eT[TT - 1];
    float iv = g_init2[c] + ls1c;
    float a0v = iv + mb + flog2(fmaxf(e0, 1e-37f));
    float refc0 = wmax64(a0v);
    double refc = (double)refc0;
    float nu = e0 * fexp2(iv + mb - refc0 - PIN);
    float accf = 1.0f, OFF = 0.0f;
    float z1=0.f,z2=0.f,z3=0.f,z4=0.f,z5=0.f,z6=0.f,z7=0.f,z8=0.f,z9=0.f;
    float Wc = 0.f;
    float r8 = mb;
    float su = 1.0f;
    float pfL = 0.f, pfc = 0.f;
    double refL = 0.0;
    v2 P1, P2, P3, P4;

    // ---- prologue block (t=0..7): per-step deadbeat locks the slope ----
    {
        float4 nA = cp[4], nB = cp[5];
        STEPS(cA.x, 0) CTRLDB(0.3f) STEPS(cA.y, 1) CTRLDB(0.3f)
        STEPS(cA.z, 2) CTRLDB(0.3f) STEPS(cA.w, 3) CTRLDB(0.3f)
        STEPS(cB.x, 4) CTRLDB(0.3f) STEPS(cB.y, 5) CTRLDB(0.3f)
        STEPS(cB.z, 6) CTRLDB(0.3f) STEPS(cB.w, 7) CTRLDB(0.3f)
        cA = pA; cB = pB; pA = nA; pB = nB;
    }

    // pack slots into pairs for the fused main loop
    P1 = (v2){z1, z2}; P2 = (v2){z3, z4}; P3 = (v2){z5, z6}; P4 = (v2){z7, z8};

    // ---- main loop: fused 2-steps, max-pin deadbeat every 4 steps ----
    for (int tb = 8; tb < tb_end; tb += 8) {
        int bi = tb >> 2;
        float4 nA = cp[bi + 4], nB = cp[bi + 5];   // prefetch t+16..t+23
        STEP2(cA.x, cA.y) STEP2(cA.z, cA.w)
        CTRL2M(0.125f)
        STEP2(cB.x, cB.y) STEP2(cB.z, cB.w)
        CTRL2M(0.125f)
        cA = pA; cB = pB; pA = nA; pB = nB;
    }

    // ---- tail block (contains lenm1): scalar steps with capture ----
    z1 = P1.x; z2 = P1.y; z3 = P2.x; z4 = P2.y;
    z5 = P3.x; z6 = P3.y; z7 = P4.x; z8 = P4.y;
    STEPS(cA.x, tb_end + 0) STEPS(cA.y, tb_end + 1)
    STEPS(cA.z, tb_end + 2) STEPS(cA.w, tb_end + 3)
    STEPS(cB.x, tb_end + 4) STEPS(cB.y, tb_end + 5)
    STEPS(cB.z, tb_end + 6) STEPS(cB.w, tb_end + 7)

    // ---- final sum over classes: all pfL share scale refL+PIN ----
    float tot = pfL;
#pragma unroll
    for (int st = 1; st < 32; st <<= 1) tot += __shfl_xor(tot, st);
    if (l == 0) {
        double a = refL + (double)PIN + (double)flog2(fmaxf(tot, 1e-37f));
        out[b] = (float)(-0.69314718055994530942 * a);
    }
}

extern "C" void kernel_launch(void* const* d_in, const int* in_sizes, int n_in,
                              void* d_out, int out_size, void* d_ws, size_t ws_size,
                              hipStream_t stream) {
    const float* feat = (const float*)d_in[0];
    const float* plr  = (const float*)d_in[1];
    const float* mu   = (const float*)d_in[2];
    const float* cov  = (const float*)d_in[3];
    const float* tl   = (const float*)d_in[4];
    const float* il   = (const float*)d_in[5];
    const int*   lens = (const int*)d_in[6];
    float* outf = (float*)d_out;
    int B = in_sizes[6];
    if (B > 8) B = 8;

    smm_setup<<<1, 64, 0, stream>>>(plr, mu, cov, tl, il);
    smm_emit<<<dim3(TT / 8, B), 256, 0, stream>>>(feat);
    smm_forward<<<B, 64, 0, stream>>>(lens, outf);
}

// Round 10
// 715.003 us; speedup vs baseline: 1.1381x; 1.1381x over previous
//
#include <hip/hip_runtime.h>
#include <math.h>

#define TT 4096
#define DD 64
#define CC 32
#define KK 20
#define TPE 4128   /* transposed eT row stride: 4096 + 32 pad for prefetch overrun */
#define L2E 1.44269504088896340736f
#define LN2f 0.69314718055994530942f
#define PIN 10.0f  /* bootstrap pf scale 2^-PIN; running pin holds accf ~ 2^0 */

typedef float v2 __attribute__((ext_vector_type(2)));

#if __has_builtin(__builtin_amdgcn_permlane32_swap)
#define HAVE_PLSWAP 1
#endif
#if __has_builtin(__builtin_amdgcn_permlane16_swap)
#define HAVE_PL16 1
#endif

// ---- static device scratch ----
__device__ __align__(16) float g_pmu[32 * 64];
__device__ __align__(16) float g_p2[64];
__device__ __align__(16) float g_mc[32];
__device__ __align__(16) float g_ls2[20 * 32];
__device__ __align__(16) float g_T[32 * 32];
__device__ __align__(16) float g_init2[32];
__device__ float g_mb;
__device__ __align__(16) float g_eT[8 * 32 * TPE];

__device__ __forceinline__ float fexp2(float x) {
#if __has_builtin(__builtin_amdgcn_exp2f)
    return __builtin_amdgcn_exp2f(x);
#else
    return __exp2f(x);
#endif
}
__device__ __forceinline__ float flog2(float x) {
#if __has_builtin(__builtin_amdgcn_logf)
    return __builtin_amdgcn_logf(x);
#else
    return __log2f(x);
#endif
}

#define RF(x) __int_as_float(__builtin_amdgcn_readfirstlane(__float_as_int(x)))

// cross-half exchange (validated r1/r2/r4/r7 — runtime select, polarity-proof)
__device__ __forceinline__ float xswap32(float x) {
#ifdef HAVE_PLSWAP
    int xi = __float_as_int(x);
    auto pr = __builtin_amdgcn_permlane32_swap(xi, xi, false, false);
    int r0 = ((const int*)&pr)[0];
    int r1 = ((const int*)&pr)[1];
    return (r0 == xi) ? __int_as_float(r1) : __int_as_float(r0);
#else
    return __shfl_xor(x, 32);
#endif
}
__device__ __forceinline__ float xswap16(float x) {
#ifdef HAVE_PL16
    int xi = __float_as_int(x);
    auto pr = __builtin_amdgcn_permlane16_swap(xi, xi, false, false);
    int r0 = ((const int*)&pr)[0];
    int r1 = ((const int*)&pr)[1];
    return (r0 == xi) ? __int_as_float(r1) : __int_as_float(r0);
#else
    return __shfl_xor(x, 16);
#endif
}

// XOR-symmetric DPP: 0xB1=xor1 0x4E=xor2 0x1B=xor3 0x141=xor7 0x140=xor15
#define DPPF(dst, src, CTRL) \
    dst = __int_as_float(__builtin_amdgcn_update_dpp(0, __float_as_int(src), (CTRL), 0xF, 0xF, 1))

// 64-lane max via XOR butterflies (r7-validated; bootstrap only)
__device__ __forceinline__ float wmax64(float x) {
    float m = x, t;
    DPPF(t, m, 0xB1);  m = fmaxf(m, t);
    DPPF(t, m, 0x4E);  m = fmaxf(m, t);
    DPPF(t, m, 0x141); m = fmaxf(m, t);
    DPPF(t, m, 0x140); m = fmaxf(m, t);
    m = fmaxf(m, xswap16(m));
    m = fmaxf(m, xswap32(m));
    return m;
}

// ---------------- setup ----------------
__global__ void smm_setup(const float* __restrict__ plr,
                          const float* __restrict__ mu,
                          const float* __restrict__ cov,
                          const float* __restrict__ tl,
                          const float* __restrict__ il) {
    int l = threadIdx.x;
    __shared__ float red[64];
    __shared__ float redp[64];
    __shared__ float muP[32];
    __shared__ float constc_s;
    float cd = cov[l * 64 + l];
    float pd = 1.0f / cd;
    red[l] = logf(cd);
    redp[l] = pd;
    __syncthreads();
    if (l == 0) {
        float s = 0.f;
        for (int i = 0; i < 64; ++i) s += red[i];
        constc_s = 64.0f * logf(2.0f * 3.14159265358979323846f) + s;
    }
    __syncthreads();
    float constc = constc_s;

    g_p2[l] = 0.5f * L2E * pd;
    for (int c2 = 0; c2 < 32; ++c2)
        g_pmu[c2 * 64 + l] = L2E * pd * mu[c2 * 64 + l];

    if (l < 32) {
        float s = 0.f;
        for (int d2 = 0; d2 < 64; ++d2) {
            float m_ = mu[l * 64 + d2];
            s += m_ * m_ / cov[d2 * 64 + d2];
        }
        g_mc[l] = -0.5f * L2E * (s + constc);
        muP[l] = s;
    }
    for (int idx = l; idx < KK * CC; idx += 64) {
        int k = idx >> 5, c2 = idx & 31;
        float lr = plr[c2];
        g_ls2[idx] = L2E * ((float)(k + 1) * lr - expf(lr) - lgammaf((float)(k + 2)));
    }
    if (l < 32) {
        int from = l;
        float mx = -1e30f;
        for (int to = 0; to < 32; ++to) mx = fmaxf(mx, tl[to * 32 + from]);
        float s = 0.f;
        for (int to = 0; to < 32; ++to) s += expf(tl[to * 32 + from] - mx);
        float inv = 1.0f / s;
        for (int to = 0; to < 32; ++to)
            g_T[to * 32 + from] = expf(tl[to * 32 + from] - mx) * inv;
    }
    if (l == 32) {
        float mx = -1e30f;
        for (int c2 = 0; c2 < 32; ++c2) mx = fmaxf(mx, il[c2]);
        float s = 0.f;
        for (int c2 = 0; c2 < 32; ++c2) s += expf(il[c2] - mx);
        float lse = mx + logf(s);
        for (int c2 = 0; c2 < 32; ++c2) g_init2[c2] = L2E * (il[c2] - lse);
    }
    __syncthreads();
    if (l == 0) {
        float trP = 0.f;
        for (int i = 0; i < 64; ++i) trP += redp[i];
        float mm = 0.f;
        for (int c2 = 0; c2 < 32; ++c2) mm += muP[c2];
        mm *= (1.0f / 32.0f);
        g_mb = -0.5f * L2E * (constc + trP + mm);
    }
}

// ---------------- emit: transposed linear emission factors ----------------
__global__ __launch_bounds__(256) void smm_emit(const float* __restrict__ feat) {
    int tid = threadIdx.x;
    int c = tid & 31, tl_ = tid >> 5;
    int t = blockIdx.x * 8 + tl_;
    int b = blockIdx.y;
    const float4* x4 = (const float4*)(feat + ((size_t)b * TT + t) * DD);
    const float4* pm4 = (const float4*)(g_pmu + c * 64);
    const float4* p24 = (const float4*)g_p2;
    float acc = g_mc[c];
#pragma unroll
    for (int i = 0; i < 16; ++i) {
        float4 xv = x4[i], pm = pm4[i], pv = p24[i];
        acc = fmaf(pm.x, xv.x, acc); acc = fmaf(-pv.x * xv.x, xv.x, acc);
        acc = fmaf(pm.y, xv.y, acc); acc = fmaf(-pv.y * xv.y, xv.y, acc);
        acc = fmaf(pm.z, xv.z, acc); acc = fmaf(-pv.z * xv.z, xv.z, acc);
        acc = fmaf(pm.w, xv.w, acc); acc = fmaf(-pv.w * xv.w, xv.w, acc);
    }
    float ev = fexp2(acc - g_mb);
    __shared__ float stage[32][9];
    stage[c][tl_] = ev;
    __syncthreads();
    int c2 = tid >> 3, j = tid & 7;
    int t0 = blockIdx.x * 8;
    int ti = (t0 + j + TT - 1) & (TT - 1);
    g_eT[((size_t)b * 32 + c2) * TPE + ti] = stage[c2][j];
}

// ---- gather + matvec + pair-combine (r4/r8 DPP form, lane ops verbatim) ----
#define GMV(PF, OUT)                                                              \
    {                                                                             \
        float G1, G2, G3, G7, G15;                                                \
        DPPF(G1, PF, 0xB1); DPPF(G2, PF, 0x4E); DPPF(G3, PF, 0x1B);               \
        DPPF(G7, PF, 0x141); DPPF(G15, PF, 0x140);                                \
        float G4, G5, G6, G8, G12, G13, G14;                                      \
        DPPF(G6, G1, 0x141); DPPF(G5, G2, 0x141); DPPF(G4, G3, 0x141);            \
        DPPF(G8, G7, 0x140); DPPF(G14, G1, 0x140); DPPF(G13, G2, 0x140);          \
        DPPF(G12, G3, 0x140);                                                     \
        float G9, G10, G11;                                                       \
        DPPF(G9, G14, 0x141); DPPF(G10, G13, 0x141); DPPF(G11, G12, 0x141);       \
        float a0 = Tr[0]*(PF); a0 = fmaf(Tr[1],G1,a0);   a0 = fmaf(Tr[2],G2,a0);   a0 = fmaf(Tr[3],G3,a0);    \
        float a1 = Tr[4]*G4;   a1 = fmaf(Tr[5],G5,a1);   a1 = fmaf(Tr[6],G6,a1);   a1 = fmaf(Tr[7],G7,a1);    \
        float a2 = Tr[8]*G8;   a2 = fmaf(Tr[9],G9,a2);   a2 = fmaf(Tr[10],G10,a2); a2 = fmaf(Tr[11],G11,a2);  \
        float a3 = Tr[12]*G12; a3 = fmaf(Tr[13],G13,a3); a3 = fmaf(Tr[14],G14,a3); a3 = fmaf(Tr[15],G15,a3);  \
        float accl_ = (a0 + a1) + (a2 + a3);                                      \
        OUT = accl_ + xswap16(xswap32(accl_));                                    \
    }

// ---- full scalar step with capture + per-step refc advance ----
#define STEPS(EV, tcur)                                                           \
    {                                                                             \
        float pf = fmaf(accf, nu, OFF);                                           \
        float naccf;                                                              \
        GMV(pf, naccf)                                                            \
        if ((tcur) == lenm1) { pfL = pf; refL = refc; }                           \
        float sg = (EV) * su;                                                     \
        float u2 = accf * nu;                                                     \
        float s0 = half ? Wc : u2;                                                \
        float e9 = z9 * sg;                                                       \
        float t9 = e9 * rr;                                                       \
        float x9 = xswap32(t9);                                                   \
        float Wn = half ? x9 : t9;                                                \
        z9 = z8*sg; z8 = z7*sg; z7 = z6*sg; z6 = z5*sg; z5 = z4*sg;               \
        z4 = z3*sg; z3 = z2*sg; z2 = z1*sg; z1 = s0*sg;                           \
        float tA = Pw1*z1; tA = fmaf(Pw2,z2,tA); tA = fmaf(Pw3,z3,tA);            \
        tA = fmaf(Pw4,z4,tA); tA = fmaf(Pw5,z5,tA);                               \
        float tB = Pw6*z6; tB = fmaf(Pw7,z7,tB); tB = fmaf(Pw8,z8,tB);            \
        tB = fmaf(Pw9,z9,tB);                                                     \
        float S = tA + tB;                                                        \
        float Sx = xswap32(S);                                                    \
        OFF = fmaxf((S + Sx) + Wn, 1e-36f);                                       \
        nu = sg * E1;                                                             \
        accf = naccf;                                                             \
        mea = naccf;                                                              \
        Wc = Wn;                                                                  \
        refc += (double)r8;                                                       \
    }

// ---- fused 2-step (r8 algebra verbatim; mea = mixed scale probe, 1-stale) ----
#define STEP2(EVA, EVB)                                                           \
    {                                                                             \
        float pfA = fmaf(accf, nu, OFF);                                          \
        float naccfA;                                                             \
        GMV(pfA, naccfA)                                                          \
        mea = naccfA;                                                             \
        float sgA = (EVA) * su;                                                   \
        float u2A = accf * nu;                                                    \
        float s0A = half ? Wc : u2A;                                              \
        float t9A = (z9 * sgA) * rr;                                              \
        float x9A = xswap32(t9A);                                                 \
        float WnA = half ? x9A : t9A;                                             \
        v2 dB = PwB1 * P1;                                                        \
        dB = __builtin_elementwise_fma(PwB2, P2, dB);                             \
        dB = __builtin_elementwise_fma(PwB3, P3, dB);                             \
        dB = __builtin_elementwise_fma(PwB4, P4, dB);                             \
        float SA = sgA * fmaf(Pw1, s0A, dB.x + dB.y);                             \
        float OFFB = fmaxf((SA + xswap32(SA)) + WnA, 1e-36f);                     \
        float nuB = sgA * E1;                                                     \
        float pfB = fmaf(naccfA, nuB, OFFB);                                      \
        float naccfB;                                                             \
        GMV(pfB, naccfB)                                                          \
        float sgB = (EVB) * su;                                                   \
        float ss = sgA * sgB;                                                     \
        float u2B = naccfA * nuB;                                                 \
        float s0B = half ? WnA : u2B;                                             \
        float t9B = (P4.y * ss) * rr;                                             \
        float x9B = xswap32(t9B);                                                 \
        float WnB = half ? x9B : t9B;                                             \
        v2 dC = PwC1 * P1;                                                        \
        dC = __builtin_elementwise_fma(PwC2, P2, dC);                             \
        dC = __builtin_elementwise_fma(PwC3, P3, dC);                             \
        dC = __builtin_elementwise_fma(PwC4, P4, dC);                             \
        float innerB = fmaf(Pw2, s0A, dC.x + dC.y);                               \
        float SB = sgB * fmaf(sgA, innerB, Pw1 * s0B);                            \
        float OFFn = fmaxf((SB + xswap32(SB)) + WnB, 1e-36f);                     \
        v2 ssv = {ss, ss};                                                        \
        z9 = P4.x * ss;                                                           \
        P4 = P3 * ssv; P3 = P2 * ssv; P2 = P1 * ssv;                              \
        v2 nP1; nP1.x = s0B * sgB; nP1.y = s0A * ss;                              \
        P1 = nP1;                                                                 \
        OFF = OFFn; nu = sgB * E1; accf = naccfB; Wc = WnB;                       \
    }

// prologue deadbeat: pin the MIXED quantity accf (readfirstlane-safe: matvec
// mixing bounds cross-lane spread to ~0.15 log2 — no flush-ratchet possible).
#define CTRLDB(gain)                                                              \
    {                                                                             \
        float err = flog2(fmaxf(RF(mea), 1e-37f));                                \
        err = fminf(fmaxf(err, -60.0f), 60.0f);                                   \
        float cs = fexp2(-err);                                                   \
        accf *= cs; OFF *= cs; Wc *= cs;                                          \
        z1*=cs; z2*=cs; z3*=cs; z4*=cs; z5*=cs;                                   \
        z6*=cs; z7*=cs; z8*=cs; z9*=cs;                                           \
        refc += (double)err;                                                      \
        r8 = fmaf(err, (gain), r8);                                               \
        su = fexp2(mb - r8);                                                      \
    }

// main-loop deadbeat: cadence 4, 1-stale probe (mea = naccfA of the preceding
// STEP2 — its RF/log2/exp2 chain hides under that STEP2's B-half issue).
#define CTRL2M(gain)                                                              \
    {                                                                             \
        float err = flog2(fmaxf(RF(mea), 1e-37f));                                \
        err = fminf(fmaxf(err, -60.0f), 60.0f);                                   \
        float cs = fexp2(-err);                                                   \
        v2 csv = {cs, cs};                                                        \
        accf *= cs; OFF *= cs; Wc *= cs; z9 *= cs;                                \
        P1 *= csv; P2 *= csv; P3 *= csv; P4 *= csv;                               \
        refc += (double)err + (double)(4.0f * r8);                                \
        r8 = fmaf(err, (gain), r8);                                               \
        su = fexp2(mb - r8);                                                      \
    }

__global__ __launch_bounds__(64, 1)
void smm_forward(const int* __restrict__ lens, float* __restrict__ out) {
    const int b = blockIdx.x;
    const int l = threadIdx.x;
    const int c = l & 31;
    const int half = l >> 5;
    const int i16 = l & 15;
    const int rb = ((l >> 4) & 1) * 16;
    const int cT = half ? (c ^ 16) : c;

    float lsr[10];
#pragma unroll
    for (int i = 0; i < 10; ++i) lsr[i] = g_ls2[(half * 10 + i) * 32 + c];

    // transition row, permuted for the XOR gather: Tr[j] pairs with p[rb + (i16^j)]
    float Tr[16];
#pragma unroll
    for (int j2 = 0; j2 < 16; ++j2) Tr[j2] = g_T[cT * 32 + rb + (i16 ^ j2)];

    float tswp = __shfl_xor(lsr[0], 32);
    float ls1c = half ? tswp : lsr[0];
    float d11s = half ? lsr[0] : tswp;

    float Pw1 = fexp2(lsr[1] - lsr[0]), Pw2 = fexp2(lsr[2] - lsr[0]);
    float Pw3 = fexp2(lsr[3] - lsr[0]), Pw4 = fexp2(lsr[4] - lsr[0]);
    float Pw5 = fexp2(lsr[5] - lsr[0]), Pw6 = fexp2(lsr[6] - lsr[0]);
    float Pw7 = fexp2(lsr[7] - lsr[0]), Pw8 = fexp2(lsr[8] - lsr[0]);
    float Pw9 = fexp2(lsr[9] - lsr[0]);
    float rr  = fexp2(d11s - lsr[0]);
    float E1  = fexp2(ls1c);

    // packed weight pairs for the fused dots
    v2 PwB1 = {Pw2, Pw3}, PwB2 = {Pw4, Pw5}, PwB3 = {Pw6, Pw7}, PwB4 = {Pw8, Pw9};
    v2 PwC1 = {Pw3, Pw4}, PwC2 = {Pw5, Pw6}, PwC3 = {Pw7, Pw8}, PwC4 = {Pw9, 0.0f};

    int len = lens[b];
    if (len < 16) len = 16;
    if (len > TT) len = TT;
    const int lenm1 = len - 1;
    const int tb_end = lenm1 & ~7;   // tail block [tb_end, tb_end+7] contains lenm1

    const float* eT = g_eT + ((size_t)b * 32 + c) * TPE;
    const float4* cp = (const float4*)eT;
    float4 cA = cp[0], cB = cp[1], pA = cp[2], pB = cp[3];

    // ---- bootstrap at t=0: pf scale 2^-PIN via wave-max of a0v ----
    float mb = g_mb;
    float e0 = eT[TT - 1];
    float iv = g_init2[c] + ls1c;
    float a0v = iv + mb + flog2(fmaxf(e0, 1e-37f));
    float refc0 = wmax64(a0v);
    double refc = (double)refc0;
    float nu = e0 * fexp2(iv + mb - refc0 - PIN);
    float accf = 1.0f, OFF = 0.0f;
    float z1=0.f,z2=0.f,z3=0.f,z4=0.f,z5=0.f,z6=0.f,z7=0.f,z8=0.f,z9=0.f;
    float Wc = 0.f;
    float r8 = mb;
    float su = 1.0f;
    float pfL = 0.f, mea = 1.0f;
    double refL = 0.0;
    v2 P1, P2, P3, P4;

    // ---- prologue block (t=0..7): per-step deadbeat locks the slope ----
    {
        float4 nA = cp[4], nB = cp[5];
        STEPS(cA.x, 0) CTRLDB(0.3f) STEPS(cA.y, 1) CTRLDB(0.3f)
        STEPS(cA.z, 2) CTRLDB(0.3f) STEPS(cA.w, 3) CTRLDB(0.3f)
        STEPS(cB.x, 4) CTRLDB(0.3f) STEPS(cB.y, 5) CTRLDB(0.3f)
        STEPS(cB.z, 6) CTRLDB(0.3f) STEPS(cB.w, 7) CTRLDB(0.3f)
        cA = pA; cB = pB; pA = nA; pB = nB;
    }

    // pack slots into pairs for the fused main loop
    P1 = (v2){z1, z2}; P2 = (v2){z3, z4}; P3 = (v2){z5, z6}; P4 = (v2){z7, z8};

    // ---- main loop: fused 2-steps, mixed-probe deadbeat every 4 steps ----
    for (int tb = 8; tb < tb_end; tb += 8) {
        int bi = tb >> 2;
        float4 nA = cp[bi + 4], nB = cp[bi + 5];   // prefetch t+16..t+23
        STEP2(cA.x, cA.y) STEP2(cA.z, cA.w)
        CTRL2M(0.125f)
        STEP2(cB.x, cB.y) STEP2(cB.z, cB.w)
        CTRL2M(0.125f)
        cA = pA; cB = pB; pA = nA; pB = nB;
    }

    // ---- tail block (contains lenm1): scalar steps with capture ----
    z1 = P1.x; z2 = P1.y; z3 = P2.x; z4 = P2.y;
    z5 = P3.x; z6 = P3.y; z7 = P4.x; z8 = P4.y;
    STEPS(cA.x, tb_end + 0) STEPS(cA.y, tb_end + 1)
    STEPS(cA.z, tb_end + 2) STEPS(cA.w, tb_end + 3)
    STEPS(cB.x, tb_end + 4) STEPS(cB.y, tb_end + 5)
    STEPS(cB.z, tb_end + 6) STEPS(cB.w, tb_end + 7)

    // ---- final sum over classes: all pfL share scale refL+PIN ----
    float tot = pfL;
#pragma unroll
    for (int st = 1; st < 32; st <<= 1) tot += __shfl_xor(tot, st);
    if (l == 0) {
        double a = refL + (double)PIN + (double)flog2(fmaxf(tot, 1e-37f));
        out[b] = (float)(-0.69314718055994530942 * a);
    }
}

extern "C" void kernel_launch(void* const* d_in, const int* in_sizes, int n_in,
                              void* d_out, int out_size, void* d_ws, size_t ws_size,
                              hipStream_t stream) {
    const float* feat = (const float*)d_in[0];
    const float* plr  = (const float*)d_in[1];
    const float* mu   = (const float*)d_in[2];
    const float* cov  = (const float*)d_in[3];
    const float* tl   = (const float*)d_in[4];
    const float* il   = (const float*)d_in[5];
    const int*   lens = (const int*)d_in[6];
    float* outf = (float*)d_out;
    int B = in_sizes[6];
    if (B > 8) B = 8;

    smm_setup<<<1, 64, 0, stream>>>(plr, mu, cov, tl, il);
    smm_emit<<<dim3(TT / 8, B), 256, 0, stream>>>(feat);
    smm_forward<<<B, 64, 0, stream>>>(lens, outf);
}